// Round 1
// baseline (755.514 us; speedup 1.0000x reference)
//
#include <hip/hip_runtime.h>
#include <hip/hip_bf16.h>
#include <math.h>

#define NN 8192
#define SS 50
#define DD 64
#define TAU_INV 2.0f
#define ALPHA 0.5f

__device__ __forceinline__ float wred64(float v) {
#pragma unroll
  for (int m = 1; m < 64; m <<= 1) v += __shfl_xor(v, m, 64);
  return v;
}

// ---------------- intra attention (GAT over sampled neighbors) + ELU --------
// grid (N, 2), block 64. One wave per node per type. lane = dim.
__global__ __launch_bounds__(64) void intra_kernel(
    const float* __restrict__ h0, const float* __restrict__ h1,
    const float* __restrict__ h2, const int* __restrict__ nei0,
    const int* __restrict__ nei1, const float* __restrict__ att0,
    const float* __restrict__ att1, float* __restrict__ e0,
    float* __restrict__ e1) {
  const int n = blockIdx.x;
  const int type = blockIdx.y;
  const float* __restrict__ h = type ? h2 : h1;
  const int* __restrict__ nei = type ? nei1 : nei0;
  const float* __restrict__ att = type ? att1 : att0;
  float* __restrict__ e = type ? e1 : e0;
  const int lane = threadIdx.x;

  __shared__ float logits[SS];
  __shared__ int idxs[SS];

  float r = h0[(size_t)n * DD + lane];
  float ref_dot = wred64(r * att[lane]);

  if (lane < SS) idxs[lane] = nei[(size_t)n * SS + lane];
  __syncthreads();

  const float attn = att[DD + lane];
  for (int s = 0; s < SS; ++s) {
    float v = h[(size_t)idxs[s] * DD + lane];
    float nd = wred64(v * attn);
    if (lane == 0) {
      float l = ref_dot + nd;
      logits[s] = l > 0.f ? l : 0.01f * l;  // leaky_relu slope 0.01
    }
  }
  __syncthreads();

  float mx = -1e30f;
  for (int s = 0; s < SS; ++s) mx = fmaxf(mx, logits[s]);
  float sum = 0.f;
  for (int s = 0; s < SS; ++s) sum += __expf(logits[s] - mx);
  float invs = 1.f / sum;
  float acc = 0.f;
  for (int s = 0; s < SS; ++s) {
    float w = __expf(logits[s] - mx) * invs;
    acc = fmaf(w, h[(size_t)idxs[s] * DD + lane], acc);
  }
  e[(size_t)n * DD + lane] = acc > 0.f ? acc : expm1f(acc);  // ELU
}

// ---------------- per-row inverse norms for h0, e0, e1 ----------------------
// grid 3*N/4, block 256 (4 waves, one row each). inv layout [arr][row].
__global__ __launch_bounds__(256) void norm_kernel(
    const float* __restrict__ h0, const float* __restrict__ e0,
    const float* __restrict__ e1, float* __restrict__ inv) {
  int gw = blockIdx.x * 4 + (threadIdx.x >> 6);
  int arr = gw >> 13, row = gw & (NN - 1);
  const float* __restrict__ src = arr == 0 ? h0 : (arr == 1 ? e0 : e1);
  float v = src[(size_t)row * DD + (threadIdx.x & 63)];
  float ss = wred64(v * v);
  if ((threadIdx.x & 63) == 0) inv[gw] = rsqrtf(ss);
}

// ---------------- diagonal sim sums (per pair) ------------------------------
// grid (N/4, 3), block 256.
__global__ __launch_bounds__(256) void diag_kernel(
    const float* __restrict__ h0, const float* __restrict__ e0,
    const float* __restrict__ e1, const float* __restrict__ inv,
    float* __restrict__ diag) {
  int p = blockIdx.y;
  const float *a, *b, *ia, *ib;
  if (p == 0)      { a = h0; b = e0; ia = inv;            ib = inv + NN;     }
  else if (p == 1) { a = h0; b = e1; ia = inv;            ib = inv + 2*NN;   }
  else             { a = e0; b = e1; ia = inv + NN;       ib = inv + 2*NN;   }
  int w = threadIdx.x >> 6, lane = threadIdx.x & 63;
  int row = blockIdx.x * 4 + w;
  float av = a[(size_t)row * DD + lane];
  float bv = b[(size_t)row * DD + lane];
  float d = wred64(av * bv) * ia[row] * ib[row] * TAU_INV;
  __shared__ float sm[4];
  if (lane == 0) sm[w] = d;
  __syncthreads();
  if (threadIdx.x == 0) atomicAdd(&diag[p], sm[0] + sm[1] + sm[2] + sm[3]);
}

// ---------------- sim tiles: accumulate exp-sums per row and per col --------
// grid (N/128, N/64, 3), block 256. 8x4 per thread, K=64.
__global__ __launch_bounds__(256) void sim_kernel(
    const float* __restrict__ h0, const float* __restrict__ e0,
    const float* __restrict__ e1, const float* __restrict__ inv,
    float* __restrict__ rowsum, float* __restrict__ colsum) {
  __shared__ float As[128][65];
  __shared__ float Bs[64][65];
  __shared__ float colAcc[64];
  int p = blockIdx.z;
  const float *a, *b, *ia, *ib;
  if (p == 0)      { a = h0; b = e0; ia = inv;          ib = inv + NN;   }
  else if (p == 1) { a = h0; b = e1; ia = inv;          ib = inv + 2*NN; }
  else             { a = e0; b = e1; ia = inv + NN;     ib = inv + 2*NN; }
  const int i0 = blockIdx.x * 128, j0 = blockIdx.y * 64;
  const int tid = threadIdx.x;

  for (int t = tid; t < 128 * 64; t += 256) {
    int r = t >> 6, c = t & 63;
    As[r][c] = a[(size_t)(i0 + r) * DD + c] * ia[i0 + r];
  }
  for (int t = tid; t < 64 * 64; t += 256) {
    int r = t >> 6, c = t & 63;
    Bs[r][c] = b[(size_t)(j0 + r) * DD + c] * ib[j0 + r];
  }
  if (tid < 64) colAcc[tid] = 0.f;
  __syncthreads();

  const int tx = tid & 15, ty = tid >> 4;
  float acc[8][4] = {};
#pragma unroll 4
  for (int k = 0; k < DD; ++k) {
    float av[8], bv[4];
#pragma unroll
    for (int r = 0; r < 8; ++r) av[r] = As[ty * 8 + r][k];
#pragma unroll
    for (int c = 0; c < 4; ++c) bv[c] = Bs[tx * 4 + c][k];
#pragma unroll
    for (int r = 0; r < 8; ++r)
#pragma unroll
      for (int c = 0; c < 4; ++c) acc[r][c] = fmaf(av[r], bv[c], acc[r][c]);
  }

  float rp[8];
  float cp[4] = {0.f, 0.f, 0.f, 0.f};
#pragma unroll
  for (int r = 0; r < 8; ++r) {
    float rs = 0.f;
#pragma unroll
    for (int c = 0; c < 4; ++c) {
      float ev = __expf(acc[r][c] * TAU_INV);
      rs += ev;
      cp[c] += ev;
    }
    rp[r] = rs;
  }
  // reduce row partials across tx (16 lanes)
#pragma unroll
  for (int r = 0; r < 8; ++r) {
#pragma unroll
    for (int m = 1; m < 16; m <<= 1) rp[r] += __shfl_xor(rp[r], m, 64);
  }
  if (tx == 0) {
#pragma unroll
    for (int r = 0; r < 8; ++r)
      atomicAdd(&rowsum[(size_t)p * NN + i0 + ty * 8 + r], rp[r]);
  }
  // reduce col partials across the wave's 4 ty-groups
#pragma unroll
  for (int c = 0; c < 4; ++c) {
    cp[c] += __shfl_xor(cp[c], 16, 64);
    cp[c] += __shfl_xor(cp[c], 32, 64);
  }
  if ((tid & 63) < 16) {
#pragma unroll
    for (int c = 0; c < 4; ++c) atomicAdd(&colAcc[tx * 4 + c], cp[c]);
  }
  __syncthreads();
  if (tid < 64) atomicAdd(&colsum[(size_t)p * NN + j0 + tid], colAcc[tid]);
}

// ---------------- semantic attention: sp[t][d] = sum_n tanh(e fc^T + b) -----
// grid (N/64, 2), block 256.
__global__ __launch_bounds__(256) void sp_kernel(
    const float* __restrict__ e0, const float* __restrict__ e1,
    const float* __restrict__ fc_w, const float* __restrict__ fc_b,
    float* __restrict__ sp) {
  __shared__ float fcw[64][65];
  __shared__ float es[64][65];
  __shared__ float part[4][64];
  const int t = blockIdx.y;
  const float* __restrict__ e = t ? e1 : e0;
  const int n0 = blockIdx.x * 64;
  const int tid = threadIdx.x;
  for (int i = tid; i < 4096; i += 256) fcw[i >> 6][i & 63] = fc_w[i];
  for (int i = tid; i < 4096; i += 256) {
    int r = i >> 6, c = i & 63;
    es[r][c] = e[(size_t)(n0 + r) * DD + c];
  }
  __syncthreads();
  const int w = tid >> 6, lane = tid & 63;
  const float b = fc_b[lane];
  float partial = 0.f;
  for (int n = w; n < 64; n += 4) {
    float acc = b;
#pragma unroll 8
    for (int k = 0; k < DD; ++k) acc = fmaf(es[n][k], fcw[lane][k], acc);
    partial += tanhf(acc);
  }
  part[w][lane] = partial;
  __syncthreads();
  if (tid < 64)
    atomicAdd(&sp[t * DD + tid],
              part[0][tid] + part[1][tid] + part[2][tid] + part[3][tid]);
}

// ---------------- finalize: loss scalar + beta ------------------------------
__global__ __launch_bounds__(256) void final_kernel(
    const float* __restrict__ rowsum, const float* __restrict__ colsum,
    const float* __restrict__ diag, const float* __restrict__ sp,
    const float* __restrict__ att_inter, float* __restrict__ beta,
    float* __restrict__ loss_out) {
  __shared__ float red[256];
  const int tid = threadIdx.x;
  const float wts[3] = {1.f, 1.f, ALPHA};
  float acc = 0.f;
  for (int p = 0; p < 3; ++p) {
    float wa = wts[p];
    for (int i = tid; i < NN; i += 256)
      acc += wa * (__logf(rowsum[p * NN + i]) + __logf(colsum[p * NN + i]));
  }
  red[tid] = acc;
  __syncthreads();
  for (int s = 128; s > 0; s >>= 1) {
    if (tid < s) red[tid] += red[tid + s];
    __syncthreads();
  }
  if (tid == 0) {
    float l = red[0] * 0.5f / (float)NN;
    l -= (wts[0] * diag[0] + wts[1] * diag[1] + wts[2] * diag[2]) / (float)NN;
    loss_out[0] = l;
  }
  // beta from sp means (wave 0)
  if (tid < 64) {
    float a_ = att_inter[tid];
    float s0 = sp[tid] * (1.f / (float)NN) * a_;
    float s1 = sp[DD + tid] * (1.f / (float)NN) * a_;
#pragma unroll
    for (int m = 1; m < 64; m <<= 1) {
      s0 += __shfl_xor(s0, m, 64);
      s1 += __shfl_xor(s1, m, 64);
    }
    if (tid == 0) {
      float mm = fmaxf(s0, s1);
      float b0 = __expf(s0 - mm), b1 = __expf(s1 - mm);
      float inv = 1.f / (b0 + b1);
      beta[0] = b0 * inv;
      beta[1] = b1 * inv;
    }
  }
}

// ---------------- z_mc = beta0*e0 + beta1*e1 --------------------------------
__global__ __launch_bounds__(256) void zmc_kernel(
    const float* __restrict__ e0, const float* __restrict__ e1,
    const float* __restrict__ beta, float* __restrict__ z) {
  int i = blockIdx.x * blockDim.x + threadIdx.x;
  float b0 = beta[0], b1 = beta[1];
  float4 a = ((const float4*)e0)[i];
  float4 b = ((const float4*)e1)[i];
  float4 o;
  o.x = b0 * a.x + b1 * b.x;
  o.y = b0 * a.y + b1 * b.y;
  o.z = b0 * a.z + b1 * b.z;
  o.w = b0 * a.w + b1 * b.w;
  ((float4*)z)[i] = o;
}

extern "C" void kernel_launch(void* const* d_in, const int* in_sizes, int n_in,
                              void* d_out, int out_size, void* d_ws,
                              size_t ws_size, hipStream_t stream) {
  const float* h0 = (const float*)d_in[0];
  const float* h1 = (const float*)d_in[1];
  const float* h2 = (const float*)d_in[2];
  const int* nei0 = (const int*)d_in[3];
  const int* nei1 = (const int*)d_in[4];
  const float* att0 = (const float*)d_in[5];
  const float* att1 = (const float*)d_in[6];
  const float* fcw = (const float*)d_in[7];
  const float* fcb = (const float*)d_in[8];
  const float* atti = (const float*)d_in[9];
  float* out = (float*)d_out;

  float* ws = (float*)d_ws;
  float* e0 = ws;                         // N*D
  float* e1 = e0 + (size_t)NN * DD;       // N*D
  float* inv = e1 + (size_t)NN * DD;      // 3*N
  float* rowsum = inv + 3 * NN;           // 3*N  (zeroed)
  float* colsum = rowsum + 3 * NN;        // 3*N  (zeroed)
  float* diag = colsum + 3 * NN;          // 3    (zeroed)
  float* sp = diag + 3;                   // 2*D  (zeroed)
  float* beta = sp + 2 * DD;              // 2

  size_t accBytes = (size_t)(3 * NN + 3 * NN + 3 + 2 * DD + 2) * sizeof(float);
  hipMemsetAsync(rowsum, 0, accBytes, stream);

  intra_kernel<<<dim3(NN, 2), 64, 0, stream>>>(h0, h1, h2, nei0, nei1, att0,
                                               att1, e0, e1);
  norm_kernel<<<dim3(3 * NN / 4), 256, 0, stream>>>(h0, e0, e1, inv);
  diag_kernel<<<dim3(NN / 4, 3), 256, 0, stream>>>(h0, e0, e1, inv, diag);
  sim_kernel<<<dim3(NN / 128, NN / 64, 3), 256, 0, stream>>>(h0, e0, e1, inv,
                                                             rowsum, colsum);
  sp_kernel<<<dim3(NN / 64, 2), 256, 0, stream>>>(e0, e1, fcw, fcb, sp);
  final_kernel<<<1, 256, 0, stream>>>(rowsum, colsum, diag, sp, atti, beta,
                                      out + (size_t)NN * DD);
  zmc_kernel<<<dim3(NN * DD / 1024), 256, 0, stream>>>(e0, e1, beta, out);
}

// Round 2
// 253.276 us; speedup vs baseline: 2.9830x; 2.9830x over previous
//
#include <hip/hip_runtime.h>
#include <hip/hip_bf16.h>
#include <math.h>

#define NN 8192
#define SS 50
#define DD 64
#define MM 20000
#define TAU_INV 2.0f
#define ALPHA 0.5f

typedef __attribute__((ext_vector_type(8))) short short8;   // 8 bf16 (4 VGPRs)
typedef __attribute__((ext_vector_type(4))) float f32x4;

__device__ __forceinline__ float wred64(float v) {
#pragma unroll
  for (int m = 1; m < 64; m <<= 1) v += __shfl_xor(v, m, 64);
  return v;
}
__device__ __forceinline__ float wredmax64(float v) {
#pragma unroll
  for (int m = 1; m < 64; m <<= 1) v = fmaxf(v, __shfl_xor(v, m, 64));
  return v;
}

// ---------------- q[t][m] = dot(h_t[m], att_t[D:2D]) ------------------------
// grid 10000, block 256 (4 waves, one row each), covers 2*M = 40000 rows.
__global__ __launch_bounds__(256) void q_kernel(
    const float* __restrict__ h1, const float* __restrict__ h2,
    const float* __restrict__ att0, const float* __restrict__ att1,
    float* __restrict__ q) {
  int gw = blockIdx.x * 4 + (threadIdx.x >> 6);
  int lane = threadIdx.x & 63;
  const float* h = gw < MM ? h1 : h2;
  const float* att = gw < MM ? att0 : att1;
  int row = gw < MM ? gw : gw - MM;
  float v = h[(size_t)row * DD + lane] * att[DD + lane];
  float s = wred64(v);
  if (lane == 0) q[gw] = s;
}

// ---------------- intra attention + ELU -------------------------------------
// grid (N/4, 2), block 256. One wave per node per type; lane = dim.
__global__ __launch_bounds__(256) void intra_kernel(
    const float* __restrict__ h0, const float* __restrict__ h1,
    const float* __restrict__ h2, const int* __restrict__ nei0,
    const int* __restrict__ nei1, const float* __restrict__ att0,
    const float* __restrict__ att1, const float* __restrict__ q,
    float* __restrict__ e0, float* __restrict__ e1) {
  __shared__ float wls[4][SS];
  __shared__ int ils[4][SS];
  const int w = threadIdx.x >> 6, lane = threadIdx.x & 63;
  const int n = blockIdx.x * 4 + w;
  const int type = blockIdx.y;
  const float* __restrict__ h = type ? h2 : h1;
  const int* __restrict__ nei = type ? nei1 : nei0;
  const float* __restrict__ att = type ? att1 : att0;
  const float* __restrict__ qq = q + (size_t)type * MM;
  float* __restrict__ e = type ? e1 : e0;

  float r = h0[(size_t)n * DD + lane];
  float ref = wred64(r * att[lane]);

  float logit = -1e30f;
  int myidx = 0;
  if (lane < SS) {
    myidx = nei[(size_t)n * SS + lane];
    float l = ref + qq[myidx];
    logit = l > 0.f ? l : 0.01f * l;  // leaky_relu slope 0.01
  }
  float mx = wredmax64(logit);
  float ev = lane < SS ? __expf(logit - mx) : 0.f;
  float sum = wred64(ev);
  if (lane < SS) {
    wls[w][lane] = ev / sum;
    ils[w][lane] = myidx;
  }
  __syncthreads();
  float acc = 0.f;
#pragma unroll 10
  for (int s = 0; s < SS; ++s)
    acc = fmaf(wls[w][s], h[(size_t)ils[w][s] * DD + lane], acc);
  e[(size_t)n * DD + lane] = acc > 0.f ? acc : expm1f(acc);  // ELU
}

// ---------------- prep: inv norms + normalized bf16 copies ------------------
// grid 6144, block 256 (4 waves, one row each). arr order: h0, e0, e1.
__global__ __launch_bounds__(256) void prep_kernel(
    const float* __restrict__ h0, const float* __restrict__ e0,
    const float* __restrict__ e1, float* __restrict__ inv,
    unsigned short* __restrict__ An, unsigned short* __restrict__ Bn,
    unsigned short* __restrict__ Cn) {
  int gw = blockIdx.x * 4 + (threadIdx.x >> 6);
  int lane = threadIdx.x & 63;
  int arr = gw >> 13, row = gw & (NN - 1);
  const float* __restrict__ src = arr == 0 ? h0 : (arr == 1 ? e0 : e1);
  unsigned short* __restrict__ dst = arr == 0 ? An : (arr == 1 ? Bn : Cn);
  float v = src[(size_t)row * DD + lane];
  float ss = wred64(v * v);
  float rs = rsqrtf(ss);
  if (lane == 0) inv[gw] = rs;
  union { __hip_bfloat16 b; unsigned short u; } cv;
  cv.b = __float2bfloat16(v * rs);
  dst[(size_t)row * DD + lane] = cv.u;
}

// ---------------- diagonal sim sums (per pair, fp32) ------------------------
__global__ __launch_bounds__(256) void diag_kernel(
    const float* __restrict__ h0, const float* __restrict__ e0,
    const float* __restrict__ e1, const float* __restrict__ inv,
    float* __restrict__ diag) {
  int p = blockIdx.y;
  const float *a, *b, *ia, *ib;
  if (p == 0)      { a = h0; b = e0; ia = inv;          ib = inv + NN;   }
  else if (p == 1) { a = h0; b = e1; ia = inv;          ib = inv + 2*NN; }
  else             { a = e0; b = e1; ia = inv + NN;     ib = inv + 2*NN; }
  int w = threadIdx.x >> 6, lane = threadIdx.x & 63;
  int row = blockIdx.x * 4 + w;
  float av = a[(size_t)row * DD + lane];
  float bv = b[(size_t)row * DD + lane];
  float d = wred64(av * bv) * ia[row] * ib[row] * TAU_INV;
  __shared__ float sm[4];
  if (lane == 0) sm[w] = d;
  __syncthreads();
  if (threadIdx.x == 0) atomicAdd(&diag[p], sm[0] + sm[1] + sm[2] + sm[3]);
}

// ---------------- sim via bf16 MFMA: exp-sums per row and per col -----------
// grid (N/128, 8, 3), block 256 = 4 waves (2x2 of 64x64). Each block covers
// 128 rows x 1024 cols (8 j-tiles of 128). Fragments loaded direct from
// global (L2-resident). A-frags register-cached across the j-loop.
__global__ __launch_bounds__(256) void sim_mfma_kernel(
    const unsigned short* __restrict__ An, const unsigned short* __restrict__ Bn,
    const unsigned short* __restrict__ Cn,
    float* __restrict__ rowsum, float* __restrict__ colsum) {
  __shared__ float colAcc[1024];
  const int p = blockIdx.z;
  const unsigned short *a, *b;
  if (p == 0)      { a = An; b = Bn; }
  else if (p == 1) { a = An; b = Cn; }
  else             { a = Bn; b = Cn; }
  float* __restrict__ rs = rowsum + (size_t)p * NN;
  float* __restrict__ cs = colsum + (size_t)p * NN;

  const int tid = threadIdx.x;
  const int w = tid >> 6, lane = tid & 63;
  const int wr = w >> 1, wc = w & 1;
  const int lr = lane & 15, lk = lane >> 4;
  const int i0 = blockIdx.x * 128 + wr * 64;

  for (int i = tid; i < 1024; i += 256) colAcc[i] = 0.f;
  __syncthreads();

  // A fragments: 16x32 tile; lane holds row (i0+rb*16+lr), k = lk*8..+7 (+kh*32)
  short8 afrag[4][2];
#pragma unroll
  for (int rb = 0; rb < 4; ++rb)
#pragma unroll
    for (int kh = 0; kh < 2; ++kh)
      afrag[rb][kh] = *reinterpret_cast<const short8*>(
          a + (size_t)(i0 + rb * 16 + lr) * DD + kh * 32 + lk * 8);

  float rowacc[4][4];
#pragma unroll
  for (int rb = 0; rb < 4; ++rb)
#pragma unroll
    for (int g = 0; g < 4; ++g) rowacc[rb][g] = 0.f;

  for (int jt = 0; jt < 8; ++jt) {
    const int j0 = blockIdx.y * 1024 + jt * 128 + wc * 64;
    short8 bfrag[4][2];
#pragma unroll
    for (int cb = 0; cb < 4; ++cb)
#pragma unroll
      for (int kh = 0; kh < 2; ++kh)
        bfrag[cb][kh] = *reinterpret_cast<const short8*>(
            b + (size_t)(j0 + cb * 16 + lr) * DD + kh * 32 + lk * 8);

    f32x4 acc[4][4];
#pragma unroll
    for (int rb = 0; rb < 4; ++rb)
#pragma unroll
      for (int cb = 0; cb < 4; ++cb) acc[rb][cb] = (f32x4){0.f, 0.f, 0.f, 0.f};

#pragma unroll
    for (int rb = 0; rb < 4; ++rb)
#pragma unroll
      for (int cb = 0; cb < 4; ++cb) {
        acc[rb][cb] = __builtin_amdgcn_mfma_f32_16x16x32_bf16(
            afrag[rb][0], bfrag[cb][0], acc[rb][cb], 0, 0, 0);
        acc[rb][cb] = __builtin_amdgcn_mfma_f32_16x16x32_bf16(
            afrag[rb][1], bfrag[cb][1], acc[rb][cb], 0, 0, 0);
      }

    // C/D layout: col = lr, row = lk*4 + g (within each 16x16 fragment)
    float colp[4] = {0.f, 0.f, 0.f, 0.f};
#pragma unroll
    for (int rb = 0; rb < 4; ++rb)
#pragma unroll
      for (int cb = 0; cb < 4; ++cb)
#pragma unroll
        for (int g = 0; g < 4; ++g) {
          float ev = __expf(acc[rb][cb][g] * TAU_INV);
          rowacc[rb][g] += ev;   // partial over cols (this lane's col set)
          colp[cb] += ev;        // partial over this lane's 16 rows
        }
    // complete col sums across the 4 lk groups, flush to LDS
#pragma unroll
    for (int cb = 0; cb < 4; ++cb) {
      float v = colp[cb];
      v += __shfl_xor(v, 16, 64);
      v += __shfl_xor(v, 32, 64);
      if (lk == 0) atomicAdd(&colAcc[jt * 128 + wc * 64 + cb * 16 + lr], v);
    }
  }

  // complete row sums across 16 cols, one global atomic per row per wave
#pragma unroll
  for (int rb = 0; rb < 4; ++rb)
#pragma unroll
    for (int g = 0; g < 4; ++g) {
      float v = rowacc[rb][g];
      v += __shfl_xor(v, 1, 64);
      v += __shfl_xor(v, 2, 64);
      v += __shfl_xor(v, 4, 64);
      v += __shfl_xor(v, 8, 64);
      if (lr == 0) atomicAdd(&rs[i0 + rb * 16 + lk * 4 + g], v);
    }
  __syncthreads();
  for (int i = tid; i < 1024; i += 256)
    atomicAdd(&cs[blockIdx.y * 1024 + i], colAcc[i]);
}

// ---------------- semantic attention: sp[t][d] = sum_n tanh(e fc^T + b) -----
__global__ __launch_bounds__(256) void sp_kernel(
    const float* __restrict__ e0, const float* __restrict__ e1,
    const float* __restrict__ fc_w, const float* __restrict__ fc_b,
    float* __restrict__ sp) {
  __shared__ float fcw[64][65];
  __shared__ float es[64][65];
  __shared__ float part[4][64];
  const int t = blockIdx.y;
  const float* __restrict__ e = t ? e1 : e0;
  const int n0 = blockIdx.x * 64;
  const int tid = threadIdx.x;
  for (int i = tid; i < 4096; i += 256) fcw[i >> 6][i & 63] = fc_w[i];
  for (int i = tid; i < 4096; i += 256) {
    int r = i >> 6, c = i & 63;
    es[r][c] = e[(size_t)(n0 + r) * DD + c];
  }
  __syncthreads();
  const int w = tid >> 6, lane = tid & 63;
  const float b = fc_b[lane];
  float partial = 0.f;
  for (int n = w; n < 64; n += 4) {
    float acc = b;
#pragma unroll 8
    for (int k = 0; k < DD; ++k) acc = fmaf(es[n][k], fcw[lane][k], acc);
    partial += tanhf(acc);
  }
  part[w][lane] = partial;
  __syncthreads();
  if (tid < 64)
    atomicAdd(&sp[t * DD + tid],
              part[0][tid] + part[1][tid] + part[2][tid] + part[3][tid]);
}

// ---------------- finalize: loss scalar + beta ------------------------------
__global__ __launch_bounds__(256) void final_kernel(
    const float* __restrict__ rowsum, const float* __restrict__ colsum,
    const float* __restrict__ diag, const float* __restrict__ sp,
    const float* __restrict__ att_inter, float* __restrict__ beta,
    float* __restrict__ loss_out) {
  __shared__ float red[256];
  const int tid = threadIdx.x;
  const float wts[3] = {1.f, 1.f, ALPHA};
  float acc = 0.f;
  for (int p = 0; p < 3; ++p) {
    float wa = wts[p];
    for (int i = tid; i < NN; i += 256)
      acc += wa * (__logf(rowsum[p * NN + i]) + __logf(colsum[p * NN + i]));
  }
  red[tid] = acc;
  __syncthreads();
  for (int s = 128; s > 0; s >>= 1) {
    if (tid < s) red[tid] += red[tid + s];
    __syncthreads();
  }
  if (tid == 0) {
    float l = red[0] * 0.5f / (float)NN;
    l -= (wts[0] * diag[0] + wts[1] * diag[1] + wts[2] * diag[2]) / (float)NN;
    loss_out[0] = l;
  }
  if (tid < 64) {
    float a_ = att_inter[tid];
    float s0 = sp[tid] * (1.f / (float)NN) * a_;
    float s1 = sp[DD + tid] * (1.f / (float)NN) * a_;
#pragma unroll
    for (int m = 1; m < 64; m <<= 1) {
      s0 += __shfl_xor(s0, m, 64);
      s1 += __shfl_xor(s1, m, 64);
    }
    if (tid == 0) {
      float mm = fmaxf(s0, s1);
      float b0 = __expf(s0 - mm), b1 = __expf(s1 - mm);
      float inv = 1.f / (b0 + b1);
      beta[0] = b0 * inv;
      beta[1] = b1 * inv;
    }
  }
}

// ---------------- z_mc = beta0*e0 + beta1*e1 --------------------------------
__global__ __launch_bounds__(256) void zmc_kernel(
    const float* __restrict__ e0, const float* __restrict__ e1,
    const float* __restrict__ beta, float* __restrict__ z) {
  int i = blockIdx.x * blockDim.x + threadIdx.x;
  float b0 = beta[0], b1 = beta[1];
  float4 a = ((const float4*)e0)[i];
  float4 b = ((const float4*)e1)[i];
  float4 o;
  o.x = b0 * a.x + b1 * b.x;
  o.y = b0 * a.y + b1 * b.y;
  o.z = b0 * a.z + b1 * b.z;
  o.w = b0 * a.w + b1 * b.w;
  ((float4*)z)[i] = o;
}

extern "C" void kernel_launch(void* const* d_in, const int* in_sizes, int n_in,
                              void* d_out, int out_size, void* d_ws,
                              size_t ws_size, hipStream_t stream) {
  const float* h0 = (const float*)d_in[0];
  const float* h1 = (const float*)d_in[1];
  const float* h2 = (const float*)d_in[2];
  const int* nei0 = (const int*)d_in[3];
  const int* nei1 = (const int*)d_in[4];
  const float* att0 = (const float*)d_in[5];
  const float* att1 = (const float*)d_in[6];
  const float* fcw = (const float*)d_in[7];
  const float* fcb = (const float*)d_in[8];
  const float* atti = (const float*)d_in[9];
  float* out = (float*)d_out;

  float* ws = (float*)d_ws;
  float* e0 = ws;                               // N*D
  float* e1 = e0 + (size_t)NN * DD;             // N*D
  float* inv = e1 + (size_t)NN * DD;            // 3*N
  float* q = inv + 3 * NN;                      // 2*M (=40000, 16B-multiple)
  unsigned short* An = (unsigned short*)(q + 2 * MM);  // N*D bf16 each
  unsigned short* Bn = An + (size_t)NN * DD;
  unsigned short* Cn = Bn + (size_t)NN * DD;
  float* rowsum = (float*)(Cn + (size_t)NN * DD);  // 3*N (zeroed)
  float* colsum = rowsum + 3 * NN;              // 3*N (zeroed)
  float* diag = colsum + 3 * NN;                // 3   (zeroed)
  float* sp = diag + 3;                         // 2*D (zeroed)
  float* beta = sp + 2 * DD;                    // 2

  size_t accBytes = (size_t)(3 * NN + 3 * NN + 3 + 2 * DD + 2) * sizeof(float);
  hipMemsetAsync(rowsum, 0, accBytes, stream);

  q_kernel<<<dim3((2 * MM) / 4), 256, 0, stream>>>(h1, h2, att0, att1, q);
  intra_kernel<<<dim3(NN / 4, 2), 256, 0, stream>>>(h0, h1, h2, nei0, nei1,
                                                    att0, att1, q, e0, e1);
  prep_kernel<<<dim3(3 * NN / 4), 256, 0, stream>>>(h0, e0, e1, inv, An, Bn, Cn);
  diag_kernel<<<dim3(NN / 4, 3), 256, 0, stream>>>(h0, e0, e1, inv, diag);
  sim_mfma_kernel<<<dim3(NN / 128, 8, 3), 256, 0, stream>>>(An, Bn, Cn,
                                                            rowsum, colsum);
  sp_kernel<<<dim3(NN / 64, 2), 256, 0, stream>>>(e0, e1, fcw, fcb, sp);
  final_kernel<<<1, 256, 0, stream>>>(rowsum, colsum, diag, sp, atti, beta,
                                      out + (size_t)NN * DD);
  zmc_kernel<<<dim3(NN * DD / 1024), 256, 0, stream>>>(e0, e1, beta, out);
}

// Round 3
// 177.593 us; speedup vs baseline: 4.2542x; 1.4262x over previous
//
#include <hip/hip_runtime.h>
#include <hip/hip_bf16.h>
#include <math.h>

#define NN 8192
#define SS 50
#define DD 64
#define MM 20000
#define TAU_INV 2.0f
#define ALPHA 0.5f
#define LOG2E_X2 2.8853900817779268f  // 2 * log2(e), folds TAU into v_exp

typedef __attribute__((ext_vector_type(8))) short short8;   // 8 bf16 (4 VGPRs)
typedef __attribute__((ext_vector_type(4))) float f32x4;

__device__ __forceinline__ float wred64(float v) {
#pragma unroll
  for (int m = 1; m < 64; m <<= 1) v += __shfl_xor(v, m, 64);
  return v;
}
__device__ __forceinline__ float wredmax64(float v) {
#pragma unroll
  for (int m = 1; m < 64; m <<= 1) v = fmaxf(v, __shfl_xor(v, m, 64));
  return v;
}
__device__ __forceinline__ float fast_exp2(float x) {
  float r;
  asm("v_exp_f32 %0, %1" : "=v"(r) : "v"(x));
  return r;
}

// ---------------- q[t][m] = dot(h_t[m], att_t[D:2D]) ------------------------
// grid 10000, block 256 (4 waves, one row each), covers 2*M = 40000 rows.
__global__ __launch_bounds__(256) void q_kernel(
    const float* __restrict__ h1, const float* __restrict__ h2,
    const float* __restrict__ att0, const float* __restrict__ att1,
    float* __restrict__ q) {
  int gw = blockIdx.x * 4 + (threadIdx.x >> 6);
  int lane = threadIdx.x & 63;
  const float* h = gw < MM ? h1 : h2;
  const float* att = gw < MM ? att0 : att1;
  int row = gw < MM ? gw : gw - MM;
  float v = h[(size_t)row * DD + lane] * att[DD + lane];
  float s = wred64(v);
  if (lane == 0) q[gw] = s;
}

// ---------------- intra attention + ELU -------------------------------------
// grid (N/4, 2), block 256. One wave per node per type; lane = dim.
__global__ __launch_bounds__(256) void intra_kernel(
    const float* __restrict__ h0, const float* __restrict__ h1,
    const float* __restrict__ h2, const int* __restrict__ nei0,
    const int* __restrict__ nei1, const float* __restrict__ att0,
    const float* __restrict__ att1, const float* __restrict__ q,
    float* __restrict__ e0, float* __restrict__ e1) {
  __shared__ float wls[4][SS];
  __shared__ int ils[4][SS];
  const int w = threadIdx.x >> 6, lane = threadIdx.x & 63;
  const int n = blockIdx.x * 4 + w;
  const int type = blockIdx.y;
  const float* __restrict__ h = type ? h2 : h1;
  const int* __restrict__ nei = type ? nei1 : nei0;
  const float* __restrict__ att = type ? att1 : att0;
  const float* __restrict__ qq = q + (size_t)type * MM;
  float* __restrict__ e = type ? e1 : e0;

  float r = h0[(size_t)n * DD + lane];
  float ref = wred64(r * att[lane]);

  float logit = -1e30f;
  int myidx = 0;
  if (lane < SS) {
    myidx = nei[(size_t)n * SS + lane];
    float l = ref + qq[myidx];
    logit = l > 0.f ? l : 0.01f * l;  // leaky_relu slope 0.01
  }
  float mx = wredmax64(logit);
  float ev = lane < SS ? __expf(logit - mx) : 0.f;
  float sum = wred64(ev);
  if (lane < SS) {
    wls[w][lane] = ev / sum;
    ils[w][lane] = myidx;
  }
  __syncthreads();
  float acc = 0.f;
#pragma unroll 10
  for (int s = 0; s < SS; ++s)
    acc = fmaf(wls[w][s], h[(size_t)ils[w][s] * DD + lane], acc);
  e[(size_t)n * DD + lane] = acc > 0.f ? acc : expm1f(acc);  // ELU
}

// ---------------- prep: normalized bf16 copies + diag partials --------------
// grid N/4 = 2048 blocks, 4 waves, one row each (all three arrays at once).
// Diagonal NT-Xent terms computed here as per-block partials (no atomics).
__global__ __launch_bounds__(256) void prep_kernel(
    const float* __restrict__ h0, const float* __restrict__ e0,
    const float* __restrict__ e1, unsigned short* __restrict__ An,
    unsigned short* __restrict__ Bn, unsigned short* __restrict__ Cn,
    float* __restrict__ diagPart) {
  __shared__ float sm[4][3];
  const int w = threadIdx.x >> 6, lane = threadIdx.x & 63;
  const int n = blockIdx.x * 4 + w;
  float v0 = h0[(size_t)n * DD + lane];
  float v1 = e0[(size_t)n * DD + lane];
  float v2 = e1[(size_t)n * DD + lane];
  float s00 = wred64(v0 * v0);
  float s11 = wred64(v1 * v1);
  float s22 = wred64(v2 * v2);
  float d01 = wred64(v0 * v1);
  float d02 = wred64(v0 * v2);
  float d12 = wred64(v1 * v2);
  float i0 = rsqrtf(s00), i1 = rsqrtf(s11), i2 = rsqrtf(s22);
  union { __hip_bfloat16 b; unsigned short u; } c0, c1, c2;
  c0.b = __float2bfloat16(v0 * i0);
  c1.b = __float2bfloat16(v1 * i1);
  c2.b = __float2bfloat16(v2 * i2);
  An[(size_t)n * DD + lane] = c0.u;
  Bn[(size_t)n * DD + lane] = c1.u;
  Cn[(size_t)n * DD + lane] = c2.u;
  if (lane == 0) {
    sm[w][0] = d01 * i0 * i1 * TAU_INV;
    sm[w][1] = d02 * i0 * i2 * TAU_INV;
    sm[w][2] = d12 * i1 * i2 * TAU_INV;
  }
  __syncthreads();
  if (threadIdx.x < 3)
    diagPart[blockIdx.x * 3 + threadIdx.x] =
        sm[0][threadIdx.x] + sm[1][threadIdx.x] + sm[2][threadIdx.x] +
        sm[3][threadIdx.x];
}

// ---------------- sim via bf16 MFMA: exp-sums per row and per col -----------
// grid (N/128, N/512, 3), block 256 = 4 waves (2x2 of 64x64). Block covers
// 128 rows x 512 cols (4 j-tiles). cb-outer keeps acc live-set at 16 VGPRs.
__global__ __launch_bounds__(256) void sim_mfma_kernel(
    const unsigned short* __restrict__ An, const unsigned short* __restrict__ Bn,
    const unsigned short* __restrict__ Cn,
    float* __restrict__ rowsum, float* __restrict__ colsum) {
  __shared__ float colAcc[512];
  const int p = blockIdx.z;
  const unsigned short *a, *b;
  if (p == 0)      { a = An; b = Bn; }
  else if (p == 1) { a = An; b = Cn; }
  else             { a = Bn; b = Cn; }
  float* __restrict__ rs = rowsum + (size_t)p * NN;
  float* __restrict__ cs = colsum + (size_t)p * NN;

  const int tid = threadIdx.x;
  const int w = tid >> 6, lane = tid & 63;
  const int wr = w >> 1, wc = w & 1;
  const int lr = lane & 15, lk = lane >> 4;
  const int i0 = blockIdx.x * 128 + wr * 64;

  for (int i = tid; i < 512; i += 256) colAcc[i] = 0.f;
  __syncthreads();

  // A fragments: lane holds row (i0+rb*16+lr), k = kh*32 + lk*8 .. +7
  short8 afrag[4][2];
#pragma unroll
  for (int rb = 0; rb < 4; ++rb)
#pragma unroll
    for (int kh = 0; kh < 2; ++kh)
      afrag[rb][kh] = *reinterpret_cast<const short8*>(
          a + (size_t)(i0 + rb * 16 + lr) * DD + kh * 32 + lk * 8);

  float rowacc[4][4];
#pragma unroll
  for (int rb = 0; rb < 4; ++rb)
#pragma unroll
    for (int g = 0; g < 4; ++g) rowacc[rb][g] = 0.f;

  for (int jt = 0; jt < 4; ++jt) {
    const int j0 = blockIdx.y * 512 + jt * 128 + wc * 64;
#pragma unroll
    for (int cb = 0; cb < 4; ++cb) {
      const short8 b0 = *reinterpret_cast<const short8*>(
          b + (size_t)(j0 + cb * 16 + lr) * DD + lk * 8);
      const short8 b1 = *reinterpret_cast<const short8*>(
          b + (size_t)(j0 + cb * 16 + lr) * DD + 32 + lk * 8);
      f32x4 acc[4];
#pragma unroll
      for (int rb = 0; rb < 4; ++rb) {
        acc[rb] = __builtin_amdgcn_mfma_f32_16x16x32_bf16(
            afrag[rb][0], b0, (f32x4){0.f, 0.f, 0.f, 0.f}, 0, 0, 0);
        acc[rb] = __builtin_amdgcn_mfma_f32_16x16x32_bf16(
            afrag[rb][1], b1, acc[rb], 0, 0, 0);
      }
      // C/D layout: col = lr, row = lk*4 + g (within each 16x16 fragment)
      float colp = 0.f;
#pragma unroll
      for (int rb = 0; rb < 4; ++rb)
#pragma unroll
        for (int g = 0; g < 4; ++g) {
          float ev = fast_exp2(acc[rb][g] * LOG2E_X2);
          rowacc[rb][g] += ev;
          colp += ev;
        }
      colp += __shfl_xor(colp, 16, 64);
      colp += __shfl_xor(colp, 32, 64);
      if (lk == 0) atomicAdd(&colAcc[jt * 128 + wc * 64 + cb * 16 + lr], colp);
    }
  }

  // complete row sums across the 16 lr lanes
#pragma unroll
  for (int rb = 0; rb < 4; ++rb)
#pragma unroll
    for (int g = 0; g < 4; ++g) {
      float v = rowacc[rb][g];
      v += __shfl_xor(v, 1, 64);
      v += __shfl_xor(v, 2, 64);
      v += __shfl_xor(v, 4, 64);
      v += __shfl_xor(v, 8, 64);
      if (lr == 0) atomicAdd(&rs[i0 + rb * 16 + lk * 4 + g], v);
    }
  __syncthreads();
  for (int i = tid; i < 512; i += 256)
    atomicAdd(&cs[blockIdx.y * 512 + i], colAcc[i]);
}

// ---------------- semantic attention: sp[t][d] = sum_n tanh(e fc^T + b) -----
__global__ __launch_bounds__(256) void sp_kernel(
    const float* __restrict__ e0, const float* __restrict__ e1,
    const float* __restrict__ fc_w, const float* __restrict__ fc_b,
    float* __restrict__ sp) {
  __shared__ float fcw[64][65];
  __shared__ float es[64][65];
  __shared__ float part[4][64];
  const int t = blockIdx.y;
  const float* __restrict__ e = t ? e1 : e0;
  const int n0 = blockIdx.x * 64;
  const int tid = threadIdx.x;
  for (int i = tid; i < 4096; i += 256) fcw[i >> 6][i & 63] = fc_w[i];
  for (int i = tid; i < 4096; i += 256) {
    int r = i >> 6, c = i & 63;
    es[r][c] = e[(size_t)(n0 + r) * DD + c];
  }
  __syncthreads();
  const int w = tid >> 6, lane = tid & 63;
  const float b = fc_b[lane];
  float partial = 0.f;
  for (int n = w; n < 64; n += 4) {
    float acc = b;
#pragma unroll 8
    for (int k = 0; k < DD; ++k) acc = fmaf(es[n][k], fcw[lane][k], acc);
    // fast tanh: (e^2x - 1)/(e^2x + 1), clamped for safety
    acc = fminf(fmaxf(acc, -15.f), 15.f);
    float tt = __expf(2.f * acc);
    partial += (tt - 1.f) * __builtin_amdgcn_rcpf(tt + 1.f);
  }
  part[w][lane] = partial;
  __syncthreads();
  if (tid < 64)
    atomicAdd(&sp[t * DD + tid],
              part[0][tid] + part[1][tid] + part[2][tid] + part[3][tid]);
}

// ---------------- finalize: loss scalar + beta ------------------------------
__global__ __launch_bounds__(256) void final_kernel(
    const float* __restrict__ rowsum, const float* __restrict__ colsum,
    const float* __restrict__ diagPart, const float* __restrict__ sp,
    const float* __restrict__ att_inter, float* __restrict__ beta,
    float* __restrict__ loss_out) {
  __shared__ float red[256];
  const int tid = threadIdx.x;
  const float wts[3] = {1.f, 1.f, ALPHA};
  float acc = 0.f;
  for (int p = 0; p < 3; ++p) {
    float wa = 0.5f * wts[p];
    for (int i = tid; i < NN; i += 256)
      acc += wa * (__logf(rowsum[p * NN + i]) + __logf(colsum[p * NN + i]));
  }
  for (int i = tid; i < 3 * (NN / 4); i += 256) {
    int pp = i % 3;
    acc -= (pp == 2 ? ALPHA : 1.f) * diagPart[i];
  }
  red[tid] = acc;
  __syncthreads();
  for (int s = 128; s > 0; s >>= 1) {
    if (tid < s) red[tid] += red[tid + s];
    __syncthreads();
  }
  if (tid == 0) loss_out[0] = red[0] / (float)NN;
  if (tid < 64) {
    float a_ = att_inter[tid];
    float s0 = sp[tid] * (1.f / (float)NN) * a_;
    float s1 = sp[DD + tid] * (1.f / (float)NN) * a_;
#pragma unroll
    for (int m = 1; m < 64; m <<= 1) {
      s0 += __shfl_xor(s0, m, 64);
      s1 += __shfl_xor(s1, m, 64);
    }
    if (tid == 0) {
      float mm = fmaxf(s0, s1);
      float b0 = __expf(s0 - mm), b1 = __expf(s1 - mm);
      float inv = 1.f / (b0 + b1);
      beta[0] = b0 * inv;
      beta[1] = b1 * inv;
    }
  }
}

// ---------------- z_mc = beta0*e0 + beta1*e1 --------------------------------
__global__ __launch_bounds__(256) void zmc_kernel(
    const float* __restrict__ e0, const float* __restrict__ e1,
    const float* __restrict__ beta, float* __restrict__ z) {
  int i = blockIdx.x * blockDim.x + threadIdx.x;
  float b0 = beta[0], b1 = beta[1];
  float4 a = ((const float4*)e0)[i];
  float4 b = ((const float4*)e1)[i];
  float4 o;
  o.x = b0 * a.x + b1 * b.x;
  o.y = b0 * a.y + b1 * b.y;
  o.z = b0 * a.z + b1 * b.z;
  o.w = b0 * a.w + b1 * b.w;
  ((float4*)z)[i] = o;
}

extern "C" void kernel_launch(void* const* d_in, const int* in_sizes, int n_in,
                              void* d_out, int out_size, void* d_ws,
                              size_t ws_size, hipStream_t stream) {
  const float* h0 = (const float*)d_in[0];
  const float* h1 = (const float*)d_in[1];
  const float* h2 = (const float*)d_in[2];
  const int* nei0 = (const int*)d_in[3];
  const int* nei1 = (const int*)d_in[4];
  const float* att0 = (const float*)d_in[5];
  const float* att1 = (const float*)d_in[6];
  const float* fcw = (const float*)d_in[7];
  const float* fcb = (const float*)d_in[8];
  const float* atti = (const float*)d_in[9];
  float* out = (float*)d_out;

  float* ws = (float*)d_ws;
  float* e0 = ws;                               // N*D
  float* e1 = e0 + (size_t)NN * DD;             // N*D
  float* q = e1 + (size_t)NN * DD;              // 2*M = 40000
  unsigned short* An = (unsigned short*)(q + 2 * MM);  // N*D bf16 each
  unsigned short* Bn = An + (size_t)NN * DD;
  unsigned short* Cn = Bn + (size_t)NN * DD;
  float* rowsum = (float*)(Cn + (size_t)NN * DD);  // 3*N (zeroed)
  float* colsum = rowsum + 3 * NN;              // 3*N (zeroed)
  float* sp = colsum + 3 * NN;                  // 2*D (zeroed)
  float* beta = sp + 2 * DD;                    // 2
  float* diagPart = beta + 2;                   // 3*(N/4)

  size_t zeroBytes = (size_t)(3 * NN + 3 * NN + 2 * DD) * sizeof(float);
  hipMemsetAsync(rowsum, 0, zeroBytes, stream);

  q_kernel<<<dim3((2 * MM) / 4), 256, 0, stream>>>(h1, h2, att0, att1, q);
  intra_kernel<<<dim3(NN / 4, 2), 256, 0, stream>>>(h0, h1, h2, nei0, nei1,
                                                    att0, att1, q, e0, e1);
  prep_kernel<<<dim3(NN / 4), 256, 0, stream>>>(h0, e0, e1, An, Bn, Cn,
                                                diagPart);
  sp_kernel<<<dim3(NN / 64, 2), 256, 0, stream>>>(e0, e1, fcw, fcb, sp);
  sim_mfma_kernel<<<dim3(NN / 128, NN / 512, 3), 256, 0, stream>>>(
      An, Bn, Cn, rowsum, colsum);
  final_kernel<<<1, 256, 0, stream>>>(rowsum, colsum, diagPart, sp, atti, beta,
                                      out + (size_t)NN * DD);
  zmc_kernel<<<dim3(NN * DD / 1024), 256, 0, stream>>>(e0, e1, beta, out);
}